// Round 1
// baseline (48.080 us; speedup 1.0000x reference)
//
#include <hip/hip_runtime.h>
#include <math.h>

#define HH 32
#define WW 32
#define PAD 34          // padded plane (zero border = SAME padding)
#define CHQ 10
#define SBS 10
#define KITERS 40

__global__ __launch_bounds__(512) void vin_kernel(
    const float* __restrict__ X,     // (bs,2,32,32)
    const int*   __restrict__ S1,    // (bs,10)
    const int*   __restrict__ S2,    // (bs,10)
    const float* __restrict__ bias,  // (150)
    const float* __restrict__ w0,    // (150,2,3,3)
    const float* __restrict__ w1,    // (150)
    const float* __restrict__ w,     // (10,1,3,3)
    const float* __restrict__ wfb,   // (10,1,3,3)
    const float* __restrict__ wo,    // (8,10)
    float* __restrict__ out,         // bs*10*8 output, then bs*10*8 softmax
    int bs)
{
    __shared__ float r_lds[PAD * PAD];
    __shared__ float v_lds[PAD * PAD];
    __shared__ float weff[19];       // [0..17] = w_eff, [18] = b_eff
    __shared__ float wpart[19 * 8];

    const int tid = threadIdx.x;
    const int b   = blockIdx.x;

    // ---- zero padded LDS planes (borders stay zero forever = SAME pad) ----
    for (int i = tid; i < PAD * PAD; i += 512) { r_lds[i] = 0.f; v_lds[i] = 0.f; }

    // ---- collapse (w0,bias) x w1 into an effective 2ch 3x3 conv ----
    if (tid < 152) {
        const int o = tid >> 3;      // 0..18
        const int p = tid & 7;
        float s = 0.f;
        if (o < 18) {
            for (int c = p; c < 150; c += 8) s += w1[c] * w0[c * 18 + o];
        } else {
            for (int c = p; c < 150; c += 8) s += w1[c] * bias[c];
        }
        wpart[tid] = s;
    }
    __syncthreads();
    if (tid < 19) {
        float s = 0.f;
        #pragma unroll
        for (int p = 0; p < 8; ++p) s += wpart[tid * 8 + p];
        weff[tid] = s;
    }
    __syncthreads();

    // ---- thread -> 2 vertically adjacent pixels ----
    const int x  = tid & 31;
    const int y0 = (tid >> 5) * 2;   // 0,2,...,30

    float we[19];
    #pragma unroll
    for (int i = 0; i < 19; ++i) we[i] = weff[i];

    // ---- r = conv(X, w_eff) + b_eff  (direct from global; X[b] is 8KB, L1-hot) ----
    const float* Xb = X + (size_t)b * 2 * HH * WW;
    #pragma unroll
    for (int dy = 0; dy < 2; ++dy) {
        const int y = y0 + dy;
        float acc = we[18];
        #pragma unroll
        for (int ci = 0; ci < 2; ++ci)
        #pragma unroll
        for (int ky = 0; ky < 3; ++ky)
        #pragma unroll
        for (int kx = 0; kx < 3; ++kx) {
            const int yy = y + ky - 1, xx = x + kx - 1;
            const float xv = (yy >= 0 && yy < HH && xx >= 0 && xx < WW)
                           ? Xb[ci * (HH * WW) + yy * WW + xx] : 0.f;
            acc += we[ci * 9 + ky * 3 + kx] * xv;
        }
        r_lds[(y + 1) * PAD + (x + 1)] = acc;
    }
    __syncthreads();

    // ---- qr = conv(r, w) per pixel (loop-invariant), v0 = max_oc qr ----
    float wr[CHQ][9];
    #pragma unroll
    for (int oc = 0; oc < CHQ; ++oc)
    #pragma unroll
    for (int k = 0; k < 9; ++k) wr[oc][k] = w[oc * 9 + k];

    float nb[4][3];
    #pragma unroll
    for (int rr = 0; rr < 4; ++rr)
    #pragma unroll
    for (int cc = 0; cc < 3; ++cc) nb[rr][cc] = r_lds[(y0 + rr) * PAD + (x + cc)];

    float qr[2][CHQ];
    float v0[2];
    #pragma unroll
    for (int dy = 0; dy < 2; ++dy) {
        float m = -1e30f;
        #pragma unroll
        for (int oc = 0; oc < CHQ; ++oc) {
            float t = 0.f;
            #pragma unroll
            for (int ky = 0; ky < 3; ++ky)
            #pragma unroll
            for (int kx = 0; kx < 3; ++kx) t += wr[oc][ky * 3 + kx] * nb[dy + ky][kx];
            qr[dy][oc] = t;
            m = fmaxf(m, t);
        }
        v0[dy] = m;
    }
    v_lds[(y0 + 1) * PAD + (x + 1)] = v0[0];
    v_lds[(y0 + 2) * PAD + (x + 1)] = v0[1];
    __syncthreads();

    // ---- value-iteration loop: v <- max_oc(qr + conv(v, w_fb)) x 39 ----
    float wf[CHQ][9];
    #pragma unroll
    for (int oc = 0; oc < CHQ; ++oc)
    #pragma unroll
    for (int k = 0; k < 9; ++k) wf[oc][k] = wfb[oc * 9 + k];

    for (int it = 0; it < KITERS - 1; ++it) {
        float vn[4][3];
        #pragma unroll
        for (int rr = 0; rr < 4; ++rr)
        #pragma unroll
        for (int cc = 0; cc < 3; ++cc) vn[rr][cc] = v_lds[(y0 + rr) * PAD + (x + cc)];

        float vnew[2];
        #pragma unroll
        for (int dy = 0; dy < 2; ++dy) {
            float m = -1e30f;
            #pragma unroll
            for (int oc = 0; oc < CHQ; ++oc) {
                float t = qr[dy][oc];
                #pragma unroll
                for (int ky = 0; ky < 3; ++ky)
                #pragma unroll
                for (int kx = 0; kx < 3; ++kx) t += wf[oc][ky * 3 + kx] * vn[dy + ky][kx];
                m = fmaxf(m, t);
            }
            vnew[dy] = m;
        }
        __syncthreads();
        v_lds[(y0 + 1) * PAD + (x + 1)] = vnew[0];
        v_lds[(y0 + 2) * PAD + (x + 1)] = vnew[1];
        __syncthreads();
    }

    // ---- final q only at the 10 gather points; 10->8 matmul + softmax ----
    if (tid < SBS) {
        const int row = b * SBS + tid;
        const int s1 = S1[row];
        const int s2 = S2[row];

        float fq[CHQ];
        #pragma unroll
        for (int oc = 0; oc < CHQ; ++oc) {
            float t = 0.f;
            #pragma unroll
            for (int ky = 0; ky < 3; ++ky)
            #pragma unroll
            for (int kx = 0; kx < 3; ++kx) {
                const int idx = (s1 + ky) * PAD + (s2 + kx);
                t += w[oc * 9 + ky * 3 + kx]   * r_lds[idx]
                   + wfb[oc * 9 + ky * 3 + kx] * v_lds[idx];
            }
            fq[oc] = t;
        }

        float o8[8];
        float mx = -1e30f;
        #pragma unroll
        for (int o = 0; o < 8; ++o) {
            float t = 0.f;
            #pragma unroll
            for (int oc = 0; oc < CHQ; ++oc) t += fq[oc] * wo[o * 10 + oc];
            o8[o] = t;
            mx = fmaxf(mx, t);
        }
        float e[8];
        float es = 0.f;
        #pragma unroll
        for (int o = 0; o < 8; ++o) { e[o] = expf(o8[o] - mx); es += e[o]; }
        const float inv = 1.f / es;

        #pragma unroll
        for (int o = 0; o < 8; ++o) {
            out[(size_t)row * 8 + o] = o8[o];
            out[(size_t)bs * SBS * 8 + (size_t)row * 8 + o] = e[o] * inv;
        }
    }
}

extern "C" void kernel_launch(void* const* d_in, const int* in_sizes, int n_in,
                              void* d_out, int out_size, void* d_ws, size_t ws_size,
                              hipStream_t stream) {
    const float* X    = (const float*)d_in[0];
    const int*   S1   = (const int*)d_in[1];
    const int*   S2   = (const int*)d_in[2];
    const float* bias = (const float*)d_in[3];
    const float* w0   = (const float*)d_in[4];
    const float* w1   = (const float*)d_in[5];
    const float* w    = (const float*)d_in[6];
    const float* wfb  = (const float*)d_in[7];
    const float* wo   = (const float*)d_in[8];
    float* out        = (float*)d_out;

    const int bs = in_sizes[0] / (2 * HH * WW);   // 256

    vin_kernel<<<bs, 512, 0, stream>>>(X, S1, S2, bias, w0, w1, w, wfb, wo, out, bs);
}

// Round 2
// 48.067 us; speedup vs baseline: 1.0003x; 1.0003x over previous
//
#include <hip/hip_runtime.h>
#include <math.h>

typedef float f2 __attribute__((ext_vector_type(2)));

#define HH 32
#define WW 32
#define PAD 34          // padded scalar plane (zero border = SAME padding)
#define PADW 34         // padded width for pair rows
#define NPK 18          // 16 pair-rows + 2 halo pair-rows
#define CHQ 10
#define SBS 10
#define KITERS 40

static __device__ __forceinline__ f2 vmax2(f2 a, f2 b) {
    f2 r; r.x = fmaxf(a.x, b.x); r.y = fmaxf(a.y, b.y); return r;
}

__global__ __launch_bounds__(512) void vin_kernel(
    const float* __restrict__ X,     // (bs,2,32,32)
    const int*   __restrict__ S1,    // (bs,10)
    const int*   __restrict__ S2,    // (bs,10)
    const float* __restrict__ bias,  // (150)
    const float* __restrict__ w0,    // (150,2,3,3)
    const float* __restrict__ w1,    // (150)
    const float* __restrict__ w,     // (10,1,3,3)
    const float* __restrict__ wfb,   // (10,1,3,3)
    const float* __restrict__ wo,    // (8,10)
    float* __restrict__ out,         // bs*10*8 output, then bs*10*8 softmax
    int bs)
{
    __shared__ float r_lds[PAD * PAD];
    __shared__ f2    vbuf[2][NPK * PADW];   // v plane as vertical float2 pairs
    __shared__ float weff[19];              // [0..17] = w_eff, [18] = b_eff
    __shared__ float wpart[19 * 8];

    const int tid = threadIdx.x;
    const int b   = blockIdx.x;

    // ---- zero padded LDS planes (borders / halo pair-rows stay zero) ----
    for (int i = tid; i < PAD * PAD; i += 512) r_lds[i] = 0.f;
    {
        f2* vz = &vbuf[0][0];
        const f2 z = (f2)(0.f);
        for (int i = tid; i < 2 * NPK * PADW; i += 512) vz[i] = z;
    }

    // ---- collapse (w0,bias) x w1 into an effective 2ch 3x3 conv ----
    if (tid < 152) {
        const int o = tid >> 3;      // 0..18
        const int p = tid & 7;
        float s = 0.f;
        if (o < 18) {
            for (int c = p; c < 150; c += 8) s += w1[c] * w0[c * 18 + o];
        } else {
            for (int c = p; c < 150; c += 8) s += w1[c] * bias[c];
        }
        wpart[tid] = s;
    }
    __syncthreads();
    if (tid < 19) {
        float s = 0.f;
        #pragma unroll
        for (int p = 0; p < 8; ++p) s += wpart[tid * 8 + p];
        weff[tid] = s;
    }
    __syncthreads();

    // ---- thread -> 2 vertically adjacent pixels ----
    const int x  = tid & 31;         // 0..31
    const int m  = tid >> 5;         // pair row 0..15  (y0 = 2m)
    const int y0 = m * 2;
    const int pr = m + 1;            // padded pair-row index
    const int cx = x + 1;            // padded col index

    float we[19];
    #pragma unroll
    for (int i = 0; i < 19; ++i) we[i] = weff[i];

    // ---- r = conv(X, w_eff) + b_eff ----
    const float* Xb = X + (size_t)b * 2 * HH * WW;
    #pragma unroll
    for (int dy = 0; dy < 2; ++dy) {
        const int y = y0 + dy;
        float acc = we[18];
        #pragma unroll
        for (int ci = 0; ci < 2; ++ci)
        #pragma unroll
        for (int ky = 0; ky < 3; ++ky)
        #pragma unroll
        for (int kx = 0; kx < 3; ++kx) {
            const int yy = y + ky - 1, xx = x + kx - 1;
            const float xv = (yy >= 0 && yy < HH && xx >= 0 && xx < WW)
                           ? Xb[ci * (HH * WW) + yy * WW + xx] : 0.f;
            acc += we[ci * 9 + ky * 3 + kx] * xv;
        }
        r_lds[(y + 1) * PAD + (x + 1)] = acc;
    }
    __syncthreads();

    // ---- qr = conv(r, w) per pixel (loop-invariant), v0 = max_oc qr ----
    float wr[CHQ][9];
    #pragma unroll
    for (int oc = 0; oc < CHQ; ++oc)
    #pragma unroll
    for (int k = 0; k < 9; ++k) wr[oc][k] = w[oc * 9 + k];

    float nb[4][3];
    #pragma unroll
    for (int rr = 0; rr < 4; ++rr)
    #pragma unroll
    for (int cc = 0; cc < 3; ++cc) nb[rr][cc] = r_lds[(y0 + rr) * PAD + (x + cc)];

    f2 qr2[CHQ];
    f2 v02;
    {
        float v0a = -1e30f, v0b = -1e30f;
        #pragma unroll
        for (int oc = 0; oc < CHQ; ++oc) {
            float t0 = 0.f, t1 = 0.f;
            #pragma unroll
            for (int ky = 0; ky < 3; ++ky)
            #pragma unroll
            for (int kx = 0; kx < 3; ++kx) {
                t0 += wr[oc][ky * 3 + kx] * nb[0 + ky][kx];
                t1 += wr[oc][ky * 3 + kx] * nb[1 + ky][kx];
            }
            qr2[oc].x = t0; qr2[oc].y = t1;
            v0a = fmaxf(v0a, t0); v0b = fmaxf(v0b, t1);
        }
        v02.x = v0a; v02.y = v0b;
    }
    const int base = pr * PADW + cx;
    vbuf[0][base] = v02;
    __syncthreads();

    // ---- value-iteration loop: v <- max_oc(qr + conv(v, w_fb)) x 39 ----
    float wf[CHQ][9];
    #pragma unroll
    for (int oc = 0; oc < CHQ; ++oc)
    #pragma unroll
    for (int k = 0; k < 9; ++k) wf[oc][k] = wfb[oc * 9 + k];

    const f2* vcur = &vbuf[0][0];
    f2*       vnxt = &vbuf[1][0];

    for (int it = 0; it < KITERS - 1; ++it) {
        // load 3 pair-rows x 3 cols of the v-pair plane
        f2 pm1[3], pm0[3], pp1[3];
        #pragma unroll
        for (int c = 0; c < 3; ++c) {
            pm1[c] = vcur[base - PADW + c - 1];
            pm0[c] = vcur[base        + c - 1];
            pp1[c] = vcur[base + PADW + c - 1];
        }
        // vertical-pair operands per kernel row (shared across all 10 oc)
        f2 a0[3], a1[3], a2[3];
        #pragma unroll
        for (int c = 0; c < 3; ++c) {
            a0[c] = __builtin_shufflevector(pm1[c], pm0[c], 1, 2); // {v[y-1],v[y]}
            a1[c] = pm0[c];                                        // {v[y],  v[y+1]}
            a2[c] = __builtin_shufflevector(pm0[c], pp1[c], 1, 2); // {v[y+1],v[y+2]}
        }

        f2 vm;
        #pragma unroll
        for (int oc = 0; oc < CHQ; ++oc) {
            f2 t = qr2[oc];
            #pragma unroll
            for (int c = 0; c < 3; ++c) {
                t += wf[oc][0 + c] * a0[c];
                t += wf[oc][3 + c] * a1[c];
                t += wf[oc][6 + c] * a2[c];
            }
            vm = (oc == 0) ? t : vmax2(vm, t);
        }

        vnxt[base] = vm;
        __syncthreads();
        const f2* tmp = vcur; vcur = vnxt; vnxt = (f2*)tmp;
    }
    // vcur now points at the final v plane (barrier from last iter done)

    // ---- final q only at the 10 gather points; 10->8 matmul + softmax ----
    if (tid < SBS) {
        const int row = b * SBS + tid;
        const int s1 = S1[row];
        const int s2 = S2[row];

        float fq[CHQ];
        #pragma unroll
        for (int oc = 0; oc < CHQ; ++oc) {
            float t = 0.f;
            #pragma unroll
            for (int ky = 0; ky < 3; ++ky)
            #pragma unroll
            for (int kx = 0; kx < 3; ++kx) {
                const int yy = s1 + ky - 1;        // -1..32
                const int xx = s2 + kx - 1;        // -1..32
                const int pry = 1 + (yy >> 1);     // arithmetic shift: -1 -> 0
                const float vv = vcur[pry * PADW + (xx + 1)][yy & 1];
                t += w[oc * 9 + ky * 3 + kx]   * r_lds[(yy + 1) * PAD + (xx + 1)]
                   + wfb[oc * 9 + ky * 3 + kx] * vv;
            }
            fq[oc] = t;
        }

        float o8[8];
        float mx = -1e30f;
        #pragma unroll
        for (int o = 0; o < 8; ++o) {
            float t = 0.f;
            #pragma unroll
            for (int oc = 0; oc < CHQ; ++oc) t += fq[oc] * wo[o * 10 + oc];
            o8[o] = t;
            mx = fmaxf(mx, t);
        }
        float e[8];
        float es = 0.f;
        #pragma unroll
        for (int o = 0; o < 8; ++o) { e[o] = expf(o8[o] - mx); es += e[o]; }
        const float inv = 1.f / es;

        #pragma unroll
        for (int o = 0; o < 8; ++o) {
            out[(size_t)row * 8 + o] = o8[o];
            out[(size_t)bs * SBS * 8 + (size_t)row * 8 + o] = e[o] * inv;
        }
    }
}

extern "C" void kernel_launch(void* const* d_in, const int* in_sizes, int n_in,
                              void* d_out, int out_size, void* d_ws, size_t ws_size,
                              hipStream_t stream) {
    const float* X    = (const float*)d_in[0];
    const int*   S1   = (const int*)d_in[1];
    const int*   S2   = (const int*)d_in[2];
    const float* bias = (const float*)d_in[3];
    const float* w0   = (const float*)d_in[4];
    const float* w1   = (const float*)d_in[5];
    const float* w    = (const float*)d_in[6];
    const float* wfb  = (const float*)d_in[7];
    const float* wo   = (const float*)d_in[8];
    float* out        = (float*)d_out;

    const int bs = in_sizes[0] / (2 * HH * WW);   // 256

    vin_kernel<<<bs, 512, 0, stream>>>(X, S1, S2, bias, w0, w1, w, wfb, wo, out, bs);
}

// Round 3
// 36.127 us; speedup vs baseline: 1.3309x; 1.3305x over previous
//
#include <hip/hip_runtime.h>
#include <math.h>

typedef float f2 __attribute__((ext_vector_type(2)));

#define HH 32
#define WW 32
#define PAD 34          // padded scalar plane (zero border = SAME padding)
#define PADW 34         // padded width (in f2 units) for pair planes
#define MROWS 18        // main pair plane rows: 16 + 2 halo
#define SROWS 17        // shifted pair plane rows: 17 (row m' = {v[2m'-1], v[2m']})
#define CHQ 10
#define SBS 10
#define KITERS 40

static __device__ __forceinline__ f2 vmax2(f2 a, f2 b) {
    f2 r; r.x = fmaxf(a.x, b.x); r.y = fmaxf(a.y, b.y); return r;
}

// packed f32 fma, weight pair in %2, broadcast LOW half to both lanes
static __device__ __forceinline__ double pkfma_lo(double a, double w, double c) {
    double d;
    asm("v_pk_fma_f32 %0, %1, %2, %3 op_sel:[0,0,0] op_sel_hi:[1,0,1]"
        : "=v"(d) : "v"(a), "v"(w), "v"(c));
    return d;
}
// broadcast HIGH half of weight pair to both lanes
static __device__ __forceinline__ double pkfma_hi(double a, double w, double c) {
    double d;
    asm("v_pk_fma_f32 %0, %1, %2, %3 op_sel:[0,1,0] op_sel_hi:[1,1,1]"
        : "=v"(d) : "v"(a), "v"(w), "v"(c));
    return d;
}

__global__ __launch_bounds__(512) void vin_kernel(
    const float* __restrict__ X,     // (bs,2,32,32)
    const int*   __restrict__ S1,    // (bs,10)
    const int*   __restrict__ S2,    // (bs,10)
    const float* __restrict__ bias,  // (150)
    const float* __restrict__ w0,    // (150,2,3,3)
    const float* __restrict__ w1,    // (150)
    const float* __restrict__ w,     // (10,1,3,3)
    const float* __restrict__ wfb,   // (10,1,3,3)
    const float* __restrict__ wo,    // (8,10)
    float* __restrict__ out,         // bs*10*8 output, then bs*10*8 softmax
    int bs)
{
    __shared__ float r_lds[PAD * PAD];
    __shared__ f2    mplane[2][MROWS * PADW];  // {v[2m], v[2m+1]} at row m+1
    __shared__ f2    splane[2][SROWS * PADW];  // {v[2m'-1], v[2m']} at row m'
    __shared__ float weff[19];                 // [0..17] = w_eff, [18] = b_eff
    __shared__ float wpart[19 * 8];

    const int tid = threadIdx.x;
    const int b   = blockIdx.x;

    // ---- zero padded LDS planes (halo rows/cols stay zero = SAME padding) ----
    for (int i = tid; i < PAD * PAD; i += 512) r_lds[i] = 0.f;
    {
        const f2 z = (f2)(0.f);
        for (int i = tid; i < 2 * MROWS * PADW; i += 512) (&mplane[0][0])[i] = z;
        for (int i = tid; i < 2 * SROWS * PADW; i += 512) (&splane[0][0])[i] = z;
    }

    // ---- collapse (w0,bias) x w1 into an effective 2ch 3x3 conv ----
    if (tid < 152) {
        const int o = tid >> 3;      // 0..18
        const int p = tid & 7;
        float s = 0.f;
        if (o < 18) {
            for (int c = p; c < 150; c += 8) s += w1[c] * w0[c * 18 + o];
        } else {
            for (int c = p; c < 150; c += 8) s += w1[c] * bias[c];
        }
        wpart[tid] = s;
    }
    __syncthreads();
    if (tid < 19) {
        float s = 0.f;
        #pragma unroll
        for (int p = 0; p < 8; ++p) s += wpart[tid * 8 + p];
        weff[tid] = s;
    }
    __syncthreads();

    // ---- thread -> 2 vertically adjacent pixels ----
    const int x  = tid & 31;         // 0..31
    const int m  = tid >> 5;         // pair row 0..15  (y0 = 2m)
    const int y0 = m * 2;
    const int cx = x + 1;            // padded col index
    const int sbase = m * PADW + cx;        // shifted plane index (row m)
    const int mbase = (m + 1) * PADW + cx;  // main plane index

    float we[19];
    #pragma unroll
    for (int i = 0; i < 19; ++i) we[i] = weff[i];

    // ---- r = conv(X, w_eff) + b_eff ----
    const float* Xb = X + (size_t)b * 2 * HH * WW;
    #pragma unroll
    for (int dy = 0; dy < 2; ++dy) {
        const int y = y0 + dy;
        float acc = we[18];
        #pragma unroll
        for (int ci = 0; ci < 2; ++ci)
        #pragma unroll
        for (int ky = 0; ky < 3; ++ky)
        #pragma unroll
        for (int kx = 0; kx < 3; ++kx) {
            const int yy = y + ky - 1, xx = x + kx - 1;
            const float xv = (yy >= 0 && yy < HH && xx >= 0 && xx < WW)
                           ? Xb[ci * (HH * WW) + yy * WW + xx] : 0.f;
            acc += we[ci * 9 + ky * 3 + kx] * xv;
        }
        r_lds[(y + 1) * PAD + (x + 1)] = acc;
    }
    __syncthreads();

    // ---- qr = conv(r, w) per pixel (loop-invariant), v0 = max_oc qr ----
    float wr[CHQ][9];
    #pragma unroll
    for (int oc = 0; oc < CHQ; ++oc)
    #pragma unroll
    for (int k = 0; k < 9; ++k) wr[oc][k] = w[oc * 9 + k];

    float nb[4][3];
    #pragma unroll
    for (int rr = 0; rr < 4; ++rr)
    #pragma unroll
    for (int cc = 0; cc < 3; ++cc) nb[rr][cc] = r_lds[(y0 + rr) * PAD + (x + cc)];

    double qrd[CHQ];
    f2 v02;
    {
        float v0a = -1e30f, v0b = -1e30f;
        #pragma unroll
        for (int oc = 0; oc < CHQ; ++oc) {
            float t0 = 0.f, t1 = 0.f;
            #pragma unroll
            for (int ky = 0; ky < 3; ++ky)
            #pragma unroll
            for (int kx = 0; kx < 3; ++kx) {
                t0 += wr[oc][ky * 3 + kx] * nb[0 + ky][kx];
                t1 += wr[oc][ky * 3 + kx] * nb[1 + ky][kx];
            }
            f2 q; q.x = t0; q.y = t1;
            qrd[oc] = __builtin_bit_cast(double, q);
            v0a = fmaxf(v0a, t0); v0b = fmaxf(v0b, t1);
        }
        v02.x = v0a; v02.y = v0b;
    }
    mplane[0][mbase] = v02;
    splane[0][sbase].y = v02.x;           // v[2m]   -> S[m].hi
    splane[0][sbase + PADW].x = v02.y;    // v[2m+1] -> S[m+1].lo
    __syncthreads();

    // ---- preload w_fb as 45 packed weight pairs (bit pattern of 2 floats) ----
    double WF[45];
    #pragma unroll
    for (int p = 0; p < 45; ++p) WF[p] = ((const double*)wfb)[p];

    // ---- value-iteration step: v <- max_oc(qr + conv(v, w_fb)) ----
#define VI_STEP(CUR, NXT) do {                                                \
        double da[9];                                                         \
        _Pragma("unroll")                                                     \
        for (int c = 0; c < 3; ++c) {                                         \
            da[0 + c] = __builtin_bit_cast(double, splane[CUR][sbase + c - 1]);        \
            da[3 + c] = __builtin_bit_cast(double, mplane[CUR][mbase + c - 1]);        \
            da[6 + c] = __builtin_bit_cast(double, splane[CUR][sbase + PADW + c - 1]); \
        }                                                                     \
        f2 vm;                                                                \
        _Pragma("unroll")                                                     \
        for (int oc = 0; oc < CHQ; ++oc) {                                    \
            double t = qrd[oc];                                               \
            _Pragma("unroll")                                                 \
            for (int j = 0; j < 9; ++j) {                                     \
                const int k = oc * 9 + j;                                     \
                if ((k & 1) == 0) t = pkfma_lo(da[j], WF[k >> 1], t);         \
                else              t = pkfma_hi(da[j], WF[k >> 1], t);         \
            }                                                                 \
            const f2 tv = __builtin_bit_cast(f2, t);                          \
            vm = (oc == 0) ? tv : vmax2(vm, tv);                              \
        }                                                                     \
        mplane[NXT][mbase] = vm;                                              \
        splane[NXT][sbase].y = vm.x;                                          \
        splane[NXT][sbase + PADW].x = vm.y;                                   \
        __syncthreads();                                                      \
    } while (0)

    // 39 steps: 19 x (0->1, 1->0) + final 0->1; result in buffers[1]
    for (int itp = 0; itp < 19; ++itp) {
        VI_STEP(0, 1);
        VI_STEP(1, 0);
    }
    VI_STEP(0, 1);

    // ---- final q only at the 10 gather points; 10->8 matmul + softmax ----
    if (tid < SBS) {
        const f2* vfin = &mplane[1][0];
        const int row = b * SBS + tid;
        const int s1 = S1[row];
        const int s2 = S2[row];

        float fq[CHQ];
        #pragma unroll
        for (int oc = 0; oc < CHQ; ++oc) {
            float t = 0.f;
            #pragma unroll
            for (int ky = 0; ky < 3; ++ky)
            #pragma unroll
            for (int kx = 0; kx < 3; ++kx) {
                const int yy = s1 + ky - 1;        // -1..32
                const int xx = s2 + kx - 1;        // -1..32
                const int pry = 1 + (yy >> 1);     // arithmetic shift: -1 -> 0
                const float vv = vfin[pry * PADW + (xx + 1)][yy & 1];
                t += w[oc * 9 + ky * 3 + kx]   * r_lds[(yy + 1) * PAD + (xx + 1)]
                   + wfb[oc * 9 + ky * 3 + kx] * vv;
            }
            fq[oc] = t;
        }

        float o8[8];
        float mx = -1e30f;
        #pragma unroll
        for (int o = 0; o < 8; ++o) {
            float t = 0.f;
            #pragma unroll
            for (int oc = 0; oc < CHQ; ++oc) t += fq[oc] * wo[o * 10 + oc];
            o8[o] = t;
            mx = fmaxf(mx, t);
        }
        float e[8];
        float es = 0.f;
        #pragma unroll
        for (int o = 0; o < 8; ++o) { e[o] = expf(o8[o] - mx); es += e[o]; }
        const float inv = 1.f / es;

        #pragma unroll
        for (int o = 0; o < 8; ++o) {
            out[(size_t)row * 8 + o] = o8[o];
            out[(size_t)bs * SBS * 8 + (size_t)row * 8 + o] = e[o] * inv;
        }
    }
}

extern "C" void kernel_launch(void* const* d_in, const int* in_sizes, int n_in,
                              void* d_out, int out_size, void* d_ws, size_t ws_size,
                              hipStream_t stream) {
    const float* X    = (const float*)d_in[0];
    const int*   S1   = (const int*)d_in[1];
    const int*   S2   = (const int*)d_in[2];
    const float* bias = (const float*)d_in[3];
    const float* w0   = (const float*)d_in[4];
    const float* w1   = (const float*)d_in[5];
    const float* w    = (const float*)d_in[6];
    const float* wfb  = (const float*)d_in[7];
    const float* wo   = (const float*)d_in[8];
    float* out        = (float*)d_out;

    const int bs = in_sizes[0] / (2 * HH * WW);   // 256

    vin_kernel<<<bs, 512, 0, stream>>>(X, S1, S2, bias, w0, w1, w, wfb, wo, out, bs);
}